// Round 22
// baseline (175.611 us; speedup 1.0000x reference)
//
#include <hip/hip_runtime.h>
#include <hip/hip_bf16.h>

typedef __attribute__((ext_vector_type(8))) short bf16x8;
typedef __attribute__((ext_vector_type(4))) short bf16x4;
typedef __attribute__((ext_vector_type(4))) float f32x4;

constexpr int NT   = 512;   // tiles
constexpr int NP   = 512;   // points (M)
constexpr int DIN  = 256;   // K
constexpr int DOUT = 256;   // N
constexpr int BN   = 128;   // N-half per block
constexpr int CHM  = 32;    // M rows per epoch
constexpr int NEP  = NP / CHM;  // 16 epochs

__device__ __forceinline__ short f2bf(float f) {
  __hip_bfloat16 h = __float2bfloat16(f);
  return __builtin_bit_cast(short, h);
}

__device__ __forceinline__ bf16x8 cvt8(f32x4 a, f32x4 b) {
  bf16x8 r;
  r[0] = f2bf(a[0]); r[1] = f2bf(a[1]); r[2] = f2bf(a[2]); r[3] = f2bf(a[3]);
  r[4] = f2bf(b[0]); r[5] = f2bf(b[1]); r[6] = f2bf(b[2]); r[7] = f2bf(b[3]);
  return r;
}

// Ws: [n=128][k=256] bf16, 64 KB. Granule = 8 elem (16 B). Reads 2-way.
__device__ __forceinline__ int wsw(int n, int k) {
  return n * DIN + (k ^ (((n ^ (n >> 2)) & 7) << 3));
}

// Xf: [m=32][k=256] f32 per buffer. 16 B granule (4 f32) XOR-swizzled by
// row&7 — applied on the gl_lds SOURCE address and on the read side
// (dest stays lane-linear, m173 pattern). g = granule index (k/4).
__device__ __forceinline__ int xg(int r, int g) {
  return r * DIN + ((g ^ (r & 7)) << 2);
}

__global__ __launch_bounds__(512, 2) void adaptive_linear_v14(
    const float* __restrict__ x,     // [NT][NP][DIN]
    const int*   __restrict__ idx,   // [NT]
    const float* __restrict__ w,     // [CH][DIN][DOUT]
    const float* __restrict__ bias,  // [DOUT]
    float*       __restrict__ out)   // [NT][NP][DOUT]
{
  __shared__ short Ws[BN * DIN];      // 64 KB
  __shared__ float Xf[2][CHM * DIN];  // 2 x 32 KB f32  (128 KB total)

  const int tid = threadIdx.x;
  const int b   = blockIdx.x;
  // XCD pairing (v12-proven): blocks b and b+8 share a tile -> same XCD.
  const int t   = (b >> 4) * 8 + (b & 7);
  const int nh  = (b >> 3) & 1;

  const int c = idx[t];
  const float* xb = x   + (size_t)t * NP * DIN;
  const float* wb = w   + (size_t)c * DIN * DOUT + nh * BN;
  float*       ob = out + (size_t)t * NP * DOUT + nh * BN;

  const int l   = tid & 63;
  const int wid = tid >> 6;            // 0..7

  // ---- x staging: pure DMA, zero registers ------------------------------
  // wave wid stages rows 4*wid..+3; one gl_lds = one full 1 KB row.
  // Source pre-swizzled per-lane so the linear LDS dest matches xg().
  auto stage_x = [&](int e, int buf) {
    #pragma unroll
    for (int i = 0; i < 4; ++i) {
      const int r = wid * 4 + i;
      const float* src = xb + (size_t)(e * CHM + r) * DIN + ((l ^ (r & 7)) << 2);
      __builtin_amdgcn_global_load_lds(
          (const __attribute__((address_space(1))) void*)src,
          (__attribute__((address_space(3))) void*)&Xf[buf][r * DIN],
          16, 0, 0);
    }
  };

  // ---- W staging (reg path, prologue only; v12-proven) ------------------
  {
    const int n4 = (tid & 31) * 4;
    const int kg = tid >> 5;           // 0..15
    f32x4 wr[4];
    #pragma unroll 1
    for (int ss = 0; ss < 4; ++ss) {
      const int k0 = ss * 64 + kg * 4;
      const float* src = wb + (size_t)k0 * DOUT + n4;
      #pragma unroll
      for (int r = 0; r < 4; ++r)
        wr[r] = *reinterpret_cast<const f32x4*>(src + (size_t)r * DOUT);
      #pragma unroll
      for (int j = 0; j < 4; ++j) {
        bf16x4 v = { f2bf(wr[0][j]), f2bf(wr[1][j]),
                     f2bf(wr[2][j]), f2bf(wr[3][j]) };
        *reinterpret_cast<bf16x4*>(&Ws[wsw(n4 + j, k0)]) = v;
      }
    }
  }

  // ---- wave decomposition: 2 (M) x 4 (N); wave owns 16 x 32 -------------
  const int wm   = wid >> 2;           // 0..1
  const int wn   = wid & 3;            // 0..3
  const int lrow = l & 15;
  const int lk   = l >> 4;             // 0..3

  float bv[2];
  #pragma unroll
  for (int fn = 0; fn < 2; ++fn)
    bv[fn] = bias[nh * BN + wn * 32 + fn * 16 + lrow];

  // ---- prologue: chunk 0 DMA issued above compute of nothing ------------
  stage_x(0, 0);
  __syncthreads();                     // full drain: W regs + chunk-0 DMA

  for (int e = 0; e < NEP; ++e) {
    // 1. issue next chunk's DMA (4 instr; in flight across the whole epoch)
    if (e < NEP - 1) stage_x(e + 1, (e + 1) & 1);

    // 2. compute: 8 K-steps of 32; A from f32 LDS with in-reg cvt
    f32x4 acc[2] = {};
    const float* xs = Xf[e & 1];
    const int r = wm * 16 + lrow;
    #pragma unroll
    for (int ks = 0; ks < 8; ++ks) {
      const int g0 = ks * 8 + lk * 2;          // granule of 8-f32 A slice
      const f32x4 va = *reinterpret_cast<const f32x4*>(&xs[xg(r, g0)]);
      const f32x4 vb = *reinterpret_cast<const f32x4*>(&xs[xg(r, g0 + 1)]);
      const bf16x8 a = cvt8(va, vb);
      const int kb = ks * 32 + lk * 8;
      #pragma unroll
      for (int fn = 0; fn < 2; ++fn) {
        const bf16x8 bb = *reinterpret_cast<const bf16x8*>(
            &Ws[wsw(wn * 32 + fn * 16 + lrow, kb)]);
        acc[fn] = __builtin_amdgcn_mfma_f32_16x16x32_bf16(a, bb, acc[fn], 0, 0, 0);
      }
    }

    // 3. epilogue: bias + plain f32 stores (stay in flight past the barrier)
    {
      const int r0w = e * CHM + wm * 16 + lk * 4;
      #pragma unroll
      for (int fn = 0; fn < 2; ++fn) {
        const int col = wn * 32 + fn * 16 + lrow;
        float* op = ob + (size_t)r0w * DOUT + col;
        #pragma unroll
        for (int rr = 0; rr < 4; ++rr)
          op[(size_t)rr * DOUT] = acc[fn][rr] + bv[fn];
      }
    }

    // 4. counted-vmcnt barrier: waits the 4 gl_lds (older than the 8
    //    stores just issued), leaves the stores in flight. lgkm drained
    //    so next epoch's reads are safe.
    if (e < NEP - 1) {
      asm volatile("s_waitcnt vmcnt(8) lgkmcnt(0)" ::: "memory");
      __builtin_amdgcn_s_barrier();
      __builtin_amdgcn_sched_barrier(0);
    }
  }
}

extern "C" void kernel_launch(void* const* d_in, const int* in_sizes, int n_in,
                              void* d_out, int out_size, void* d_ws, size_t ws_size,
                              hipStream_t stream) {
  const float* x    = (const float*)d_in[0];
  const int*   idx  = (const int*)d_in[1];
  const float* w    = (const float*)d_in[2];
  const float* bias = (const float*)d_in[3];
  float* out = (float*)d_out;

  adaptive_linear_v14<<<NT * 2, 512, 0, stream>>>(x, idx, w, bias, out);
}

// Round 23
// 133.432 us; speedup vs baseline: 1.3161x; 1.3161x over previous
//
#include <hip/hip_runtime.h>
#include <hip/hip_bf16.h>

typedef __attribute__((ext_vector_type(8))) short bf16x8;
typedef __attribute__((ext_vector_type(4))) short bf16x4;
typedef __attribute__((ext_vector_type(4))) float f32x4;

constexpr int NT   = 512;   // tiles
constexpr int NP   = 512;   // points (M)
constexpr int DIN  = 256;   // K
constexpr int DOUT = 256;   // N
constexpr int BN   = 128;   // N-half per block
constexpr int CHM  = 64;    // M rows per epoch
constexpr int NEP  = NP / CHM;  // 8 epochs

__device__ __forceinline__ short f2bf(float f) {
  __hip_bfloat16 h = __float2bfloat16(f);
  return __builtin_bit_cast(short, h);
}

// Workgroup barrier WITHOUT the vmcnt(0) drain __syncthreads() implies.
__device__ __forceinline__ void wg_barrier() {
  asm volatile("s_waitcnt lgkmcnt(0)" ::: "memory");
  __builtin_amdgcn_s_barrier();
  __builtin_amdgcn_sched_barrier(0);
}

// Ws: [n=128][k=256] bf16, 64 KB. Granule = 8 elem (16 B).
__device__ __forceinline__ int wsw(int n, int k) {
  return n * DIN + (k ^ (((n ^ (n >> 2)) & 7) << 3));
}

// Xs: [m=64][k=256] bf16, 32 KB per buffer.
__device__ __forceinline__ int xsw(int m, int k) {
  return m * DIN + (k ^ ((m & 7) << 3));
}

__global__ __launch_bounds__(512, 2) void adaptive_linear_v15(
    const float* __restrict__ x,     // [NT][NP][DIN]
    const int*   __restrict__ idx,   // [NT]
    const float* __restrict__ w,     // [CH][DIN][DOUT]
    const float* __restrict__ bias,  // [DOUT]
    float*       __restrict__ out)   // [NT][NP][DOUT]
{
  __shared__ short Ws[BN * DIN];      // 64 KB
  __shared__ short Xs[2][CHM * DIN];  // 2 x 32 KB  (128 KB total)

  const int tid = threadIdx.x;
  const int b   = blockIdx.x;
  // XCD pairing (v12-proven): blocks b and b+8 share a tile -> same XCD.
  const int t   = (b >> 4) * 8 + (b & 7);
  const int nh  = (b >> 3) & 1;

  const int c = idx[t];
  const float* xb = x   + (size_t)t * NP * DIN;
  const float* wb = w   + (size_t)c * DIN * DOUT + nh * BN;
  float*       ob = out + (size_t)t * NP * DOUT + nh * BN;

  const int l   = tid & 63;
  const int wid = tid >> 6;            // 0..7

  // ---- W staging (all 8 waves, prologue only; v12-proven) ---------------
  {
    const int n4 = (tid & 31) * 4;
    const int kg = tid >> 5;           // 0..15
    f32x4 wr[4];
    #pragma unroll 1
    for (int ss = 0; ss < 4; ++ss) {
      const int k0 = ss * 64 + kg * 4;
      const float* src = wb + (size_t)k0 * DOUT + n4;
      #pragma unroll
      for (int r = 0; r < 4; ++r)
        wr[r] = *reinterpret_cast<const f32x4*>(src + (size_t)r * DOUT);
      #pragma unroll
      for (int j = 0; j < 4; ++j) {
        bf16x4 v = { f2bf(wr[0][j]), f2bf(wr[1][j]),
                     f2bf(wr[2][j]), f2bf(wr[3][j]) };
        *reinterpret_cast<bf16x4*>(&Ws[wsw(n4 + j, k0)]) = v;
      }
    }
  }

  // ---- roles (v13-proven) -----------------------------------------------
  const bool producer = (wid < 4);
  const int  p = wid;                  // producer: rows p*16 .. p*16+15
  const int  q = wid - 4;              // consumer: rows q*16 within chunk

  // producer: 16 full 1 KB row-loads back-to-back (64 staging VGPRs)
  f32x4 xr[16];
  auto load_x = [&](int e) {
    const float* base = xb + (size_t)e * CHM * DIN + (size_t)(p * 16) * DIN + l * 4;
    #pragma unroll
    for (int i = 0; i < 16; ++i)
      xr[i] = *reinterpret_cast<const f32x4*>(base + (size_t)i * DIN);
  };
  auto write_x = [&](int buf) {        // cvt + one b64 write per row
    #pragma unroll
    for (int i = 0; i < 16; ++i) {
      bf16x4 v = { f2bf(xr[i][0]), f2bf(xr[i][1]),
                   f2bf(xr[i][2]), f2bf(xr[i][3]) };
      *reinterpret_cast<bf16x4*>(&Xs[buf][xsw(p * 16 + i, l * 4)]) = v;
    }
  };

  // consumer state
  const int lrow = l & 15;
  const int lk   = l >> 4;             // 0..3
  // Swapped-operand C-layout: lane holds row m = q*16+lrow, cols
  // n0(j) = j*16 + lk*4 .. +3  -> bias loads as float4.
  f32x4 bv4[8];
  if (!producer) {
    #pragma unroll
    for (int j = 0; j < 8; ++j)
      bv4[j] = *reinterpret_cast<const f32x4*>(&bias[nh * BN + j * 16 + lk * 4]);
  }

  // ---- prologue ---------------------------------------------------------
  if (producer) load_x(0);             // flies under the W stage above
  if (producer) write_x(0);
  wg_barrier();

  // ---- main loop: 8 epochs ----------------------------------------------
  for (int e = 0; e < NEP; ++e) {
    if (producer) {
      if (e < NEP - 1) {
        load_x(e + 1);                 // 64 KB/CU burst in flight
        write_x((e + 1) & 1);          // counted vmcnt on xr only
      }
    } else {
      f32x4 acc[8] = {};
      const short* xbuf = Xs[e & 1];
      #pragma unroll
      for (int ks = 0; ks < 8; ++ks) {
        const int kb = ks * 32 + lk * 8;
        const bf16x8 a = *reinterpret_cast<const bf16x8*>(
            &xbuf[xsw(q * 16 + lrow, kb)]);
        #pragma unroll
        for (int j = 0; j < 8; ++j) {
          const bf16x8 bb = *reinterpret_cast<const bf16x8*>(
              &Ws[wsw(j * 16 + lrow, kb)]);
          // SWAPPED operands: D = W_frag x x_frag -> lane holds 4
          // consecutive n (cols) for fixed m (row) -> wide stores.
          acc[j] = __builtin_amdgcn_mfma_f32_16x16x32_bf16(bb, a, acc[j], 0, 0, 0);
        }
      }
      // epilogue: bias (float4) + ONE dwordx4 store per fragment
      const int m = e * CHM + q * 16 + lrow;
      float* op = ob + (size_t)m * DOUT;
      #pragma unroll
      for (int j = 0; j < 8; ++j) {
        f32x4 v;
        #pragma unroll
        for (int rr = 0; rr < 4; ++rr) v[rr] = acc[j][rr] + bv4[j][rr];
        *reinterpret_cast<f32x4*>(op + j * 16 + lk * 4) = v;
      }
    }
    if (e < NEP - 1) wg_barrier();     // publish buffer swap
  }
}

extern "C" void kernel_launch(void* const* d_in, const int* in_sizes, int n_in,
                              void* d_out, int out_size, void* d_ws, size_t ws_size,
                              hipStream_t stream) {
  const float* x    = (const float*)d_in[0];
  const int*   idx  = (const int*)d_in[1];
  const float* w    = (const float*)d_in[2];
  const float* bias = (const float*)d_in[3];
  float* out = (float*)d_out;

  adaptive_linear_v15<<<NT * 2, 512, 0, stream>>>(x, idx, w, bias, out);
}